// Round 3
// baseline (1224.510 us; speedup 1.0000x reference)
//
#include <hip/hip_runtime.h>
#include <hip/hip_bf16.h>

// DecoderPreLN2 on MI355X: bf16 MFMA pipeline.
// L=4, D=1024, H=16, HD=64, B=8, Tq=512, Tk=1024.
// Workspace layout (~104 MB required):
//   encB [8192][1024] bf16, wqT [4][1024][1024] bf16, wkvT [4][2048][1024] bf16,
//   xbuf [4096][1024] f32, hbuf/qbuf [4096][1024] bf16, kbuf [8192][1024] bf16,
//   vT [8][1024(d)][1024(tok)] bf16.

typedef __attribute__((ext_vector_type(8))) short   bf16x8;   // storage for 8 bf16
typedef __attribute__((ext_vector_type(8))) __bf16  bf16x8v;  // MFMA operand type
typedef __attribute__((ext_vector_type(4))) short   s16x4;
typedef __attribute__((ext_vector_type(4))) float   f32x4;

__device__ inline short bf16s(float f) {
  __hip_bfloat16 h = __float2bfloat16(f);
  return *reinterpret_cast<short*>(&h);
}

__device__ inline f32x4 mfma16x16x32(bf16x8 a, bf16x8 b, f32x4 c) {
  return __builtin_amdgcn_mfma_f32_16x16x32_bf16(
      __builtin_bit_cast(bf16x8v, a), __builtin_bit_cast(bf16x8v, b), c, 0, 0, 0);
}

// ---------------- conversions ----------------
__global__ __launch_bounds__(256) void conv_bf16_kernel(const float* __restrict__ in,
                                                        short* __restrict__ out) {
  int i = (blockIdx.x * 256 + threadIdx.x) * 4;
  float4 v = *reinterpret_cast<const float4*>(in + i);
  s16x4 o; o.x = bf16s(v.x); o.y = bf16s(v.y); o.z = bf16s(v.z); o.w = bf16s(v.w);
  *reinterpret_cast<s16x4*>(out + i) = o;
}

// transpose 1024x1024 fp32 -> bf16 W^T; z: 0-3 wq, 4-7 wk, 8-11 wv
__global__ __launch_bounds__(256) void transpose_w_kernel(
    const float* __restrict__ wq, const float* __restrict__ wk, const float* __restrict__ wv,
    short* __restrict__ wqT, short* __restrict__ wkvT) {
  int mat = blockIdx.z;
  const float* src; short* dst;
  if (mat < 4)      { src = wq + (long)mat * 1048576;       dst = wqT  + (long)mat * 1048576; }
  else if (mat < 8) { src = wk + (long)(mat - 4) * 1048576; dst = wkvT + (long)(mat - 4) * 2097152; }
  else              { src = wv + (long)(mat - 8) * 1048576; dst = wkvT + (long)(mat - 8) * 2097152 + 1048576; }
  __shared__ float t[32][33];
  int tx = threadIdx.x, ty = threadIdx.y;
  int x0 = blockIdx.x * 32, y0 = blockIdx.y * 32;
  #pragma unroll
  for (int j = 0; j < 32; j += 8)
    t[ty + j][tx] = src[(long)(y0 + ty + j) * 1024 + x0 + tx];
  __syncthreads();
  #pragma unroll
  for (int j = 0; j < 32; j += 8)
    dst[(long)(x0 + ty + j) * 1024 + y0 + tx] = bf16s(t[tx][ty + j]);
}

__global__ __launch_bounds__(256) void gather_kernel(const int* __restrict__ ids,
                                                     const float* __restrict__ emb,
                                                     float* __restrict__ x) {
  int row = blockIdx.x;
  long id = ids[row];
  float4 v = reinterpret_cast<const float4*>(emb + id * 1024)[threadIdx.x];
  reinterpret_cast<float4*>(x + (long)row * 1024)[threadIdx.x] = v;
}

// ---------------- layernorm (fp32 in, bf16 out) ----------------
__global__ __launch_bounds__(256) void ln_kernel(const float* __restrict__ x,
                                                 const float* __restrict__ g,
                                                 const float* __restrict__ b,
                                                 short* __restrict__ h) {
  int row = blockIdx.x, t = threadIdx.x;
  float4 v = reinterpret_cast<const float4*>(x + (long)row * 1024)[t];
  float s  = v.x + v.y + v.z + v.w;
  float sq = v.x * v.x + v.y * v.y + v.z * v.z + v.w * v.w;
  #pragma unroll
  for (int m = 32; m >= 1; m >>= 1) { s += __shfl_xor(s, m); sq += __shfl_xor(sq, m); }
  __shared__ float red[8];
  int w = t >> 6;
  if ((t & 63) == 0) { red[w * 2] = s; red[w * 2 + 1] = sq; }
  __syncthreads();
  s  = red[0] + red[2] + red[4] + red[6];
  sq = red[1] + red[3] + red[5] + red[7];
  float mu  = s * 0.0009765625f;
  float var = sq * 0.0009765625f - mu * mu;
  float rs  = rsqrtf(var + 1e-5f);
  float4 gg = reinterpret_cast<const float4*>(g)[t];
  float4 bb = reinterpret_cast<const float4*>(b)[t];
  s16x4 o;
  o.x = bf16s((v.x - mu) * rs * gg.x + bb.x);
  o.y = bf16s((v.y - mu) * rs * gg.y + bb.y);
  o.z = bf16s((v.z - mu) * rs * gg.z + bb.z);
  o.w = bf16s((v.w - mu) * rs * gg.w + bb.w);
  reinterpret_cast<s16x4*>(h + (long)row * 1024)[t] = o;
}

// ---------------- GEMM: C[M,N] = A[M,1024] @ WT[N,1024]^T + bias ----------------
// m97 structure: 128x128 tile, BK=64, 4 waves 2x2, global_load_lds w=16,
// XOR swizzle (chunk ^= row&7) on both stage-source and ds_read (rule #21).
// KV=1: N=2048; cols<1024 -> K (row-major bf16), cols>=1024 -> V transposed into vT.
template <int KV>
__global__ __launch_bounds__(256, 2) void gemm_kernel(
    const short* __restrict__ A, const short* __restrict__ WT,
    const float* __restrict__ bias0, const float* __restrict__ bias1,
    short* __restrict__ out0, short* __restrict__ out1) {
  __shared__ union {
    struct { short a[128 * 64]; short b[128 * 64]; } s;  // 32 KiB staging
    short c[4][64 * 72];                                  // 36 KiB epilogue restage
  } lds;

  const int t = threadIdx.x;
  const int lane = t & 63, w = t >> 6;
  const int lo = lane & 15, hi = lane >> 4;
  const int wr = w >> 1, wc = w & 1;
  const long bm0 = (long)blockIdx.x * 128, bn0 = (long)blockIdx.y * 128;

  f32x4 acc[4][4] = {};

  const int srow = t >> 3;  // 0..31
  const int sc = t & 7;     // 16B chunk within 128B row

  for (int kt = 0; kt < 16; ++kt) {
    __syncthreads();
    #pragma unroll
    for (int p = 0; p < 4; ++p) {
      const int row = p * 32 + srow;
      const int cs = sc ^ (row & 7);  // inverse-swizzled global source (m201 pattern)
      __builtin_amdgcn_global_load_lds(
          (const __attribute__((address_space(1))) void*)(A + (bm0 + row) * 1024 + kt * 64 + cs * 8),
          (__attribute__((address_space(3))) void*)&lds.s.a[row * 64 + sc * 8], 16, 0, 0);
      __builtin_amdgcn_global_load_lds(
          (const __attribute__((address_space(1))) void*)(WT + (bn0 + row) * 1024 + kt * 64 + cs * 8),
          (__attribute__((address_space(3))) void*)&lds.s.b[row * 64 + sc * 8], 16, 0, 0);
    }
    __syncthreads();  // drains vmcnt (compiler-emitted) -> staged tile visible
    #pragma unroll
    for (int kk = 0; kk < 2; ++kk) {
      bf16x8 af[4], bfr[4];
      #pragma unroll
      for (int i = 0; i < 4; ++i) {
        const int ar = wr * 64 + i * 16 + lo;
        af[i] = *reinterpret_cast<const bf16x8*>(
            &lds.s.a[ar * 64 + (((kk * 4 + hi) ^ (ar & 7)) * 8)]);
        const int br = wc * 64 + i * 16 + lo;
        bfr[i] = *reinterpret_cast<const bf16x8*>(
            &lds.s.b[br * 64 + (((kk * 4 + hi) ^ (br & 7)) * 8)]);
      }
      #pragma unroll
      for (int i = 0; i < 4; ++i)
        #pragma unroll
        for (int j = 0; j < 4; ++j)
          acc[i][j] = mfma16x16x32(af[i], bfr[j], acc[i][j]);
    }
  }

  const bool vpath = KV && (bn0 >= 1024);
  float bval[4];
  #pragma unroll
  for (int j = 0; j < 4; ++j) {
    const int col = (int)bn0 + wc * 64 + j * 16 + lo;
    bval[j] = vpath ? bias1[col - 1024] : bias0[col];
  }

  if (vpath) {
    // V: store transposed vT[(b*1024 + dfull)*1024 + tok]; 4 regs = 4 consecutive toks.
    const int bidx = (int)(bm0 >> 10);
    const int tk0  = (int)(bm0 & 1023);
    #pragma unroll
    for (int i = 0; i < 4; ++i) {
      const int tok = tk0 + wr * 64 + i * 16 + 4 * hi;
      #pragma unroll
      for (int j = 0; j < 4; ++j) {
        const int dfull = (int)bn0 - 1024 + wc * 64 + j * 16 + lo;
        s16x4 pk;
        #pragma unroll
        for (int r = 0; r < 4; ++r) pk[r] = bf16s(acc[i][j][r] + bval[j]);
        *reinterpret_cast<s16x4*>(out1 + ((long)(bidx * 1024 + dfull)) * 1024 + tok) = pk;
      }
    }
  } else {
    // Q/K: restage through LDS for 16B coalesced stores.
    __syncthreads();  // everyone done reading s.a/s.b before c overwrites
    #pragma unroll
    for (int i = 0; i < 4; ++i)
      #pragma unroll
      for (int j = 0; j < 4; ++j)
        #pragma unroll
        for (int r = 0; r < 4; ++r)
          lds.c[w][(i * 16 + 4 * hi + r) * 72 + j * 16 + lo] = bf16s(acc[i][j][r] + bval[j]);
    asm volatile("s_waitcnt lgkmcnt(0)" ::: "memory");
    #pragma unroll
    for (int ps = 0; ps < 8; ++ps) {
      const int rr = ps * 8 + (lane >> 3);
      const int cc = (lane & 7) * 8;
      bf16x8 vv = *reinterpret_cast<const bf16x8*>(&lds.c[w][rr * 72 + cc]);
      *reinterpret_cast<bf16x8*>(out0 + (bm0 + wr * 64 + rr) * 1024 + bn0 + wc * 64 + cc) = vv;
    }
  }
}

// ---------------- flash cross-attention ----------------
// grid (B*H=128, Tq/64=8); 4 waves, wave owns 16 q-rows; 32-key tiles, online softmax.
__global__ __launch_bounds__(256) void attn_kernel(
    const short* __restrict__ qbuf, const short* __restrict__ kbuf,
    const short* __restrict__ vT, const float* __restrict__ mask,
    float* __restrict__ dst) {
  __shared__ short pl[4][16 * 40];  // per-wave P tile, 80B row stride (16B-aligned, ~conflict-free)
  const int b = blockIdx.x >> 4, h = blockIdx.x & 15;
  const int t = threadIdx.x, w = t >> 6, lane = t & 63;
  const int lo = lane & 15, hi = lane >> 4;
  const int q0 = blockIdx.y * 64 + w * 16;

  const short* qrow = qbuf + (long)(b * 512 + q0 + lo) * 1024 + h * 64;
  const bf16x8 aq0 = *reinterpret_cast<const bf16x8*>(qrow + hi * 8);
  const bf16x8 aq1 = *reinterpret_cast<const bf16x8*>(qrow + 32 + hi * 8);

  f32x4 o[4] = {};
  float m_r[4] = {-1e30f, -1e30f, -1e30f, -1e30f};
  float l_r[4] = {};
  const float scale = 0.125f;
  const float* mrow = mask + b * 1024;
  short* plw = pl[w];

  for (int kb = 0; kb < 32; ++kb) {
    const short* kbase = kbuf + (long)(b * 1024 + kb * 32) * 1024 + h * 64;
    bf16x8 b00 = *reinterpret_cast<const bf16x8*>(kbase + (long)lo * 1024 + hi * 8);
    bf16x8 b01 = *reinterpret_cast<const bf16x8*>(kbase + (long)lo * 1024 + 32 + hi * 8);
    bf16x8 b10 = *reinterpret_cast<const bf16x8*>(kbase + (long)(16 + lo) * 1024 + hi * 8);
    bf16x8 b11 = *reinterpret_cast<const bf16x8*>(kbase + (long)(16 + lo) * 1024 + 32 + hi * 8);
    f32x4 z = {0.f, 0.f, 0.f, 0.f};
    f32x4 s0 = mfma16x16x32(aq0, b00, z);
    s0 = mfma16x16x32(aq1, b01, s0);
    f32x4 s1 = mfma16x16x32(aq0, b10, z);
    s1 = mfma16x16x32(aq1, b11, s1);

    const float mk0 = mrow[kb * 32 + lo];
    const float mk1 = mrow[kb * 32 + 16 + lo];

    float p0[4], p1[4], lm[4];
    #pragma unroll
    for (int r = 0; r < 4; ++r) {
      p0[r] = s0[r] * scale + mk0;
      p1[r] = s1[r] * scale + mk1;
      lm[r] = fmaxf(p0[r], p1[r]);
    }
    #pragma unroll
    for (int mm = 1; mm <= 8; mm <<= 1)
      #pragma unroll
      for (int r = 0; r < 4; ++r) lm[r] = fmaxf(lm[r], __shfl_xor(lm[r], mm));

    float alpha[4], ts[4];
    #pragma unroll
    for (int r = 0; r < 4; ++r) {
      const float mn = fmaxf(m_r[r], lm[r]);
      alpha[r] = __expf(m_r[r] - mn);
      m_r[r] = mn;
      p0[r] = __expf(p0[r] - mn);
      p1[r] = __expf(p1[r] - mn);
      ts[r] = p0[r] + p1[r];
    }
    #pragma unroll
    for (int mm = 1; mm <= 8; mm <<= 1)
      #pragma unroll
      for (int r = 0; r < 4; ++r) ts[r] += __shfl_xor(ts[r], mm);

    #pragma unroll
    for (int r = 0; r < 4; ++r) {
      l_r[r] = l_r[r] * alpha[r] + ts[r];
      o[0][r] *= alpha[r]; o[1][r] *= alpha[r]; o[2][r] *= alpha[r]; o[3][r] *= alpha[r];
      plw[(4 * hi + r) * 40 + lo]      = bf16s(p0[r]);
      plw[(4 * hi + r) * 40 + 16 + lo] = bf16s(p1[r]);
    }
    asm volatile("s_waitcnt lgkmcnt(0)" ::: "memory");  // P visible wave-wide (same-wave RAW)
    const bf16x8 pa = *reinterpret_cast<const bf16x8*>(&plw[lo * 40 + hi * 8]);
    const short* vbase = vT + ((long)(b * 1024 + h * 64)) * 1024 + kb * 32;
    #pragma unroll
    for (int nd = 0; nd < 4; ++nd) {
      bf16x8 bv = *reinterpret_cast<const bf16x8*>(vbase + (long)(nd * 16 + lo) * 1024 + hi * 8);
      o[nd] = mfma16x16x32(pa, bv, o[nd]);
    }
  }

  #pragma unroll
  for (int r = 0; r < 4; ++r) {
    const float invl = 1.0f / l_r[r];
    float* drow = dst + (long)(b * 512 + q0 + 4 * hi + r) * 1024 + h * 64;
    #pragma unroll
    for (int nd = 0; nd < 4; ++nd) drow[nd * 16 + lo] = o[nd][r] * invl;
  }
}

// ---------------- host ----------------
extern "C" void kernel_launch(void* const* d_in, const int* in_sizes, int n_in,
                              void* d_out, int out_size, void* d_ws, size_t ws_size,
                              hipStream_t stream) {
  const int*   ids  = (const int*)d_in[0];
  const float* enc  = (const float*)d_in[1];
  const float* mask = (const float*)d_in[2];
  const float* emb  = (const float*)d_in[3];
  const float* ln_g = (const float*)d_in[4];
  const float* ln_b = (const float*)d_in[5];
  const float* wq   = (const float*)d_in[6];
  const float* bq   = (const float*)d_in[7];
  const float* wk   = (const float*)d_in[8];
  const float* bk   = (const float*)d_in[9];
  const float* wv   = (const float*)d_in[10];
  const float* bv   = (const float*)d_in[11];
  float* out = (float*)d_out;

  char* ws = (char*)d_ws;
  short* encB = (short*)ws; ws += (long)8192 * 1024 * 2;
  short* wqT  = (short*)ws; ws += (long)4 * 1024 * 1024 * 2;
  short* wkvT = (short*)ws; ws += (long)4 * 2048 * 1024 * 2;
  float* xbuf = (float*)ws; ws += (long)4096 * 1024 * 4;
  short* hbuf = (short*)ws; ws += (long)4096 * 1024 * 2;
  short* qbuf = (short*)ws; ws += (long)4096 * 1024 * 2;
  short* kbuf = (short*)ws; ws += (long)8192 * 1024 * 2;
  short* vT   = (short*)ws; ws += (long)8192 * 1024 * 2;

  conv_bf16_kernel<<<8192, 256, 0, stream>>>(enc, encB);
  transpose_w_kernel<<<dim3(32, 32, 12), dim3(32, 8), 0, stream>>>(wq, wk, wv, wqT, wkvT);
  gather_kernel<<<4096, 256, 0, stream>>>(ids, emb, xbuf);

  for (int i = 0; i < 4; ++i) {
    ln_kernel<<<4096, 256, 0, stream>>>(xbuf, ln_g + i * 1024, ln_b + i * 1024, hbuf);
    gemm_kernel<0><<<dim3(32, 8), 256, 0, stream>>>(
        hbuf, wqT + (long)i * 1024 * 1024, bq + i * 1024, nullptr, qbuf, nullptr);
    gemm_kernel<1><<<dim3(64, 16), 256, 0, stream>>>(
        encB, wkvT + (long)i * 2048 * 1024, bk + i * 1024, bv + i * 1024, kbuf, vT);
    float* dst = (i == 3) ? out : xbuf;
    attn_kernel<<<dim3(128, 8), 256, 0, stream>>>(qbuf, kbuf, vT, mask, dst);
  }
}

// Round 4
// 1214.223 us; speedup vs baseline: 1.0085x; 1.0085x over previous
//
#include <hip/hip_runtime.h>
#include <hip/hip_bf16.h>

// DecoderPreLN2 on MI355X: bf16 MFMA pipeline, round 4.
// L=4, D=1024, H=16, HD=64, B=8, Tq=512, Tk=1024.
// Changes vs r3: (1) all 4 layers' K/V projections batched into one GEMM
// (M=8192, N=8192, K=1024) — KV is x-independent; (2) attention: 64-key
// tiles, defer-max (T13), setprio (T5), swizzled 128B-stride P tile.

typedef __attribute__((ext_vector_type(8))) short   bf16x8;   // storage for 8 bf16
typedef __attribute__((ext_vector_type(8))) __bf16  bf16x8v;  // MFMA operand type
typedef __attribute__((ext_vector_type(4))) short   s16x4;
typedef __attribute__((ext_vector_type(4))) float   f32x4;

__device__ inline short bf16s(float f) {
  __hip_bfloat16 h = __float2bfloat16(f);
  return *reinterpret_cast<short*>(&h);
}

__device__ inline f32x4 mfma16x16x32(bf16x8 a, bf16x8 b, f32x4 c) {
  return __builtin_amdgcn_mfma_f32_16x16x32_bf16(
      __builtin_bit_cast(bf16x8v, a), __builtin_bit_cast(bf16x8v, b), c, 0, 0, 0);
}

// ---------------- conversions ----------------
__global__ __launch_bounds__(256) void conv_bf16_kernel(const float* __restrict__ in,
                                                        short* __restrict__ out) {
  int i = (blockIdx.x * 256 + threadIdx.x) * 4;
  float4 v = *reinterpret_cast<const float4*>(in + i);
  s16x4 o; o.x = bf16s(v.x); o.y = bf16s(v.y); o.z = bf16s(v.z); o.w = bf16s(v.w);
  *reinterpret_cast<s16x4*>(out + i) = o;
}

// transpose 1024x1024 fp32 -> bf16 W^T; z: 0-3 wq, 4-7 wk, 8-11 wv
__global__ __launch_bounds__(256) void transpose_w_kernel(
    const float* __restrict__ wq, const float* __restrict__ wk, const float* __restrict__ wv,
    short* __restrict__ wqT, short* __restrict__ wkvT) {
  int mat = blockIdx.z;
  const float* src; short* dst;
  if (mat < 4)      { src = wq + (long)mat * 1048576;       dst = wqT  + (long)mat * 1048576; }
  else if (mat < 8) { src = wk + (long)(mat - 4) * 1048576; dst = wkvT + (long)(mat - 4) * 2097152; }
  else              { src = wv + (long)(mat - 8) * 1048576; dst = wkvT + (long)(mat - 8) * 2097152 + 1048576; }
  __shared__ float t[32][33];
  int tx = threadIdx.x, ty = threadIdx.y;
  int x0 = blockIdx.x * 32, y0 = blockIdx.y * 32;
  #pragma unroll
  for (int j = 0; j < 32; j += 8)
    t[ty + j][tx] = src[(long)(y0 + ty + j) * 1024 + x0 + tx];
  __syncthreads();
  #pragma unroll
  for (int j = 0; j < 32; j += 8)
    dst[(long)(x0 + ty + j) * 1024 + y0 + tx] = bf16s(t[tx][ty + j]);
}

__global__ __launch_bounds__(256) void gather_kernel(const int* __restrict__ ids,
                                                     const float* __restrict__ emb,
                                                     float* __restrict__ x) {
  int row = blockIdx.x;
  long id = ids[row];
  float4 v = reinterpret_cast<const float4*>(emb + id * 1024)[threadIdx.x];
  reinterpret_cast<float4*>(x + (long)row * 1024)[threadIdx.x] = v;
}

// ---------------- layernorm (fp32 in, bf16 out) ----------------
__global__ __launch_bounds__(256) void ln_kernel(const float* __restrict__ x,
                                                 const float* __restrict__ g,
                                                 const float* __restrict__ b,
                                                 short* __restrict__ h) {
  int row = blockIdx.x, t = threadIdx.x;
  float4 v = reinterpret_cast<const float4*>(x + (long)row * 1024)[t];
  float s  = v.x + v.y + v.z + v.w;
  float sq = v.x * v.x + v.y * v.y + v.z * v.z + v.w * v.w;
  #pragma unroll
  for (int m = 32; m >= 1; m >>= 1) { s += __shfl_xor(s, m); sq += __shfl_xor(sq, m); }
  __shared__ float red[8];
  int w = t >> 6;
  if ((t & 63) == 0) { red[w * 2] = s; red[w * 2 + 1] = sq; }
  __syncthreads();
  s  = red[0] + red[2] + red[4] + red[6];
  sq = red[1] + red[3] + red[5] + red[7];
  float mu  = s * 0.0009765625f;
  float var = sq * 0.0009765625f - mu * mu;
  float rs  = rsqrtf(var + 1e-5f);
  float4 gg = reinterpret_cast<const float4*>(g)[t];
  float4 bb = reinterpret_cast<const float4*>(b)[t];
  s16x4 o;
  o.x = bf16s((v.x - mu) * rs * gg.x + bb.x);
  o.y = bf16s((v.y - mu) * rs * gg.y + bb.y);
  o.z = bf16s((v.z - mu) * rs * gg.z + bb.z);
  o.w = bf16s((v.w - mu) * rs * gg.w + bb.w);
  reinterpret_cast<s16x4*>(h + (long)row * 1024)[t] = o;
}

// ---------------- GEMM: C[M,N] = A[M,1024] @ WT[N,1024]^T + bias ----------------
// m97 structure: 128x128 tile, BK=64, 4 waves 2x2, global_load_lds w=16,
// XOR swizzle (chunk ^= row&7) on both stage-source and ds_read (rule #21).
// KV=0: Q proj (grid 32x8). KV=1: batched 4-layer K/V proj (grid 64x64);
// N-global 8192 = layer*2048 + [K 0..1023 | V 1024..2047]. V goes transposed
// into vT[layer][b][d][tok].
template <int KV>
__global__ __launch_bounds__(256, 2) void gemm_kernel(
    const short* __restrict__ A, const short* __restrict__ WT,
    const float* __restrict__ bias0, const float* __restrict__ bias1,
    short* __restrict__ out0, short* __restrict__ out1) {
  __shared__ union {
    struct { short a[128 * 64]; short b[128 * 64]; } s;  // 32 KiB staging
    short c[4][64 * 72];                                  // 36 KiB epilogue restage
  } lds;

  const int t = threadIdx.x;
  const int lane = t & 63, w = t >> 6;
  const int lo = lane & 15, hi = lane >> 4;
  const int wr = w >> 1, wc = w & 1;
  const long bm0 = (long)blockIdx.x * 128;
  const long bn0g = (long)blockIdx.y * 128;           // global N
  const int  layer = KV ? (int)(bn0g >> 11) : 0;
  const long bn0 = KV ? (bn0g & 2047) : bn0g;          // within-layer N
  const short* WTl = KV ? WT + (long)layer * 2097152 : WT;

  f32x4 acc[4][4] = {};

  const int srow = t >> 3;  // 0..31
  const int sc = t & 7;     // 16B chunk within 128B row

  for (int kt = 0; kt < 16; ++kt) {
    __syncthreads();
    #pragma unroll
    for (int p = 0; p < 4; ++p) {
      const int row = p * 32 + srow;
      const int cs = sc ^ (row & 7);  // inverse-swizzled global source (m201 pattern)
      __builtin_amdgcn_global_load_lds(
          (const __attribute__((address_space(1))) void*)(A + (bm0 + row) * 1024 + kt * 64 + cs * 8),
          (__attribute__((address_space(3))) void*)&lds.s.a[row * 64 + sc * 8], 16, 0, 0);
      __builtin_amdgcn_global_load_lds(
          (const __attribute__((address_space(1))) void*)(WTl + (bn0 + row) * 1024 + kt * 64 + cs * 8),
          (__attribute__((address_space(3))) void*)&lds.s.b[row * 64 + sc * 8], 16, 0, 0);
    }
    __syncthreads();  // drains vmcnt (compiler-emitted) -> staged tile visible
    #pragma unroll
    for (int kk = 0; kk < 2; ++kk) {
      bf16x8 af[4], bfr[4];
      #pragma unroll
      for (int i = 0; i < 4; ++i) {
        const int ar = wr * 64 + i * 16 + lo;
        af[i] = *reinterpret_cast<const bf16x8*>(
            &lds.s.a[ar * 64 + (((kk * 4 + hi) ^ (ar & 7)) * 8)]);
        const int br = wc * 64 + i * 16 + lo;
        bfr[i] = *reinterpret_cast<const bf16x8*>(
            &lds.s.b[br * 64 + (((kk * 4 + hi) ^ (br & 7)) * 8)]);
      }
      __builtin_amdgcn_s_setprio(1);
      #pragma unroll
      for (int i = 0; i < 4; ++i)
        #pragma unroll
        for (int j = 0; j < 4; ++j)
          acc[i][j] = mfma16x16x32(af[i], bfr[j], acc[i][j]);
      __builtin_amdgcn_s_setprio(0);
    }
  }

  const bool vpath = KV && (bn0 >= 1024);
  float bval[4];
  #pragma unroll
  for (int j = 0; j < 4; ++j) {
    const int col = (int)bn0 + wc * 64 + j * 16 + lo;
    bval[j] = KV ? (vpath ? bias1[layer * 1024 + col - 1024] : bias0[layer * 1024 + col])
                 : bias0[col];
  }
  const long lofs = (long)layer * 8388608;  // 8192*1024 per layer

  if (vpath) {
    // V: store transposed vT[layer][(b*1024 + dfull)*1024 + tok]; 4 regs = 4 toks.
    const int bidx = (int)(bm0 >> 10);
    const int tk0  = (int)(bm0 & 1023);
    #pragma unroll
    for (int i = 0; i < 4; ++i) {
      const int tok = tk0 + wr * 64 + i * 16 + 4 * hi;
      #pragma unroll
      for (int j = 0; j < 4; ++j) {
        const int dfull = (int)bn0 - 1024 + wc * 64 + j * 16 + lo;
        s16x4 pk;
        #pragma unroll
        for (int r = 0; r < 4; ++r) pk[r] = bf16s(acc[i][j][r] + bval[j]);
        *reinterpret_cast<s16x4*>(out1 + lofs + ((long)(bidx * 1024 + dfull)) * 1024 + tok) = pk;
      }
    }
  } else {
    // Q/K: restage through LDS for 16B coalesced stores.
    __syncthreads();  // everyone done reading s.a/s.b before c overwrites
    #pragma unroll
    for (int i = 0; i < 4; ++i)
      #pragma unroll
      for (int j = 0; j < 4; ++j)
        #pragma unroll
        for (int r = 0; r < 4; ++r)
          lds.c[w][(i * 16 + 4 * hi + r) * 72 + j * 16 + lo] = bf16s(acc[i][j][r] + bval[j]);
    asm volatile("s_waitcnt lgkmcnt(0)" ::: "memory");
    #pragma unroll
    for (int ps = 0; ps < 8; ++ps) {
      const int rr = ps * 8 + (lane >> 3);
      const int cc = (lane & 7) * 8;
      bf16x8 vv = *reinterpret_cast<const bf16x8*>(&lds.c[w][rr * 72 + cc]);
      *reinterpret_cast<bf16x8*>(out0 + lofs + (bm0 + wr * 64 + rr) * 1024 + bn0 + wc * 64 + cc) = vv;
    }
  }
}

// ---------------- flash cross-attention ----------------
// grid (B*H=128, Tq/64=8); 4 waves, wave owns 16 q-rows; 64-key tiles,
// online softmax with defer-max (T13, THR=8), setprio around MFMA (T5).
// P tile: [16 q][64 key] bf16, 128B row stride, XOR swizzle byte^=(row&7)<<4
// applied on BOTH the b16 writes and the b128 reads (same involution).
__global__ __launch_bounds__(256) void attn_kernel(
    const short* __restrict__ qbuf, const short* __restrict__ kbuf,
    const short* __restrict__ vT, const float* __restrict__ mask,
    float* __restrict__ dst) {
  __shared__ short pl[4][16 * 64];  // 2 KiB per wave
  const int b = blockIdx.x >> 4, h = blockIdx.x & 15;
  const int t = threadIdx.x, w = t >> 6, lane = t & 63;
  const int lo = lane & 15, hi = lane >> 4;
  const int q0 = blockIdx.y * 64 + w * 16;

  const short* qrow = qbuf + (long)(b * 512 + q0 + lo) * 1024 + h * 64;
  const bf16x8 aq0 = *reinterpret_cast<const bf16x8*>(qrow + hi * 8);
  const bf16x8 aq1 = *reinterpret_cast<const bf16x8*>(qrow + 32 + hi * 8);

  f32x4 o[4] = {};
  float m_r[4] = {-1e30f, -1e30f, -1e30f, -1e30f};
  float l_r[4] = {};
  const float scale = 0.125f;
  const float* mrow = mask + b * 1024;
  char* plw = (char*)pl[w];

  for (int kb = 0; kb < 16; ++kb) {
    // ---- QK^T over 64 keys (4 sub-tiles of 16) ----
    const short* kbase = kbuf + (long)(b * 1024 + kb * 64) * 1024 + h * 64;
    f32x4 s[4];
    __builtin_amdgcn_s_setprio(1);
    #pragma unroll
    for (int kt = 0; kt < 4; ++kt) {
      bf16x8 k0 = *reinterpret_cast<const bf16x8*>(kbase + (long)(kt * 16 + lo) * 1024 + hi * 8);
      bf16x8 k1 = *reinterpret_cast<const bf16x8*>(kbase + (long)(kt * 16 + lo) * 1024 + 32 + hi * 8);
      f32x4 z = {0.f, 0.f, 0.f, 0.f};
      s[kt] = mfma16x16x32(aq0, k0, z);
      s[kt] = mfma16x16x32(aq1, k1, s[kt]);
    }
    __builtin_amdgcn_s_setprio(0);

    // ---- softmax (keys on lo within sub-tile, q-row = 4*hi+r) ----
    float mk[4];
    #pragma unroll
    for (int kt = 0; kt < 4; ++kt) mk[kt] = mrow[kb * 64 + kt * 16 + lo];

    float p[4][4], lm[4];
    #pragma unroll
    for (int r = 0; r < 4; ++r) {
      p[0][r] = s[0][r] * scale + mk[0];
      p[1][r] = s[1][r] * scale + mk[1];
      p[2][r] = s[2][r] * scale + mk[2];
      p[3][r] = s[3][r] * scale + mk[3];
      lm[r] = fmaxf(fmaxf(p[0][r], p[1][r]), fmaxf(p[2][r], p[3][r]));
    }
    #pragma unroll
    for (int mm = 1; mm <= 8; mm <<= 1)
      #pragma unroll
      for (int r = 0; r < 4; ++r) lm[r] = fmaxf(lm[r], __shfl_xor(lm[r], mm));

    // defer-max (T13): rescale only if tile max exceeds running max by >8.
    bool need = false;
    #pragma unroll
    for (int r = 0; r < 4; ++r) need = need || (lm[r] > m_r[r] + 8.0f);
    if (need) {
      #pragma unroll
      for (int r = 0; r < 4; ++r) {
        const float mn = fmaxf(m_r[r], lm[r]);
        const float al = __expf(m_r[r] - mn);
        m_r[r] = mn;
        l_r[r] *= al;
        o[0][r] *= al; o[1][r] *= al; o[2][r] *= al; o[3][r] *= al;
      }
    }

    float ts[4];
    #pragma unroll
    for (int r = 0; r < 4; ++r) {
      p[0][r] = __expf(p[0][r] - m_r[r]);
      p[1][r] = __expf(p[1][r] - m_r[r]);
      p[2][r] = __expf(p[2][r] - m_r[r]);
      p[3][r] = __expf(p[3][r] - m_r[r]);
      ts[r] = (p[0][r] + p[1][r]) + (p[2][r] + p[3][r]);
    }
    #pragma unroll
    for (int mm = 1; mm <= 8; mm <<= 1)
      #pragma unroll
      for (int r = 0; r < 4; ++r) ts[r] += __shfl_xor(ts[r], mm);
    #pragma unroll
    for (int r = 0; r < 4; ++r) l_r[r] += ts[r];

    // ---- P -> LDS (swizzled), then read back as PV A-fragments ----
    #pragma unroll
    for (int kt = 0; kt < 4; ++kt)
      #pragma unroll
      for (int r = 0; r < 4; ++r) {
        const int row = 4 * hi + r;
        const int byte = (row * 128 + (kt * 16 + lo) * 2) ^ ((row & 7) << 4);
        *reinterpret_cast<short*>(plw + byte) = bf16s(p[kt][r]);
      }
    asm volatile("s_waitcnt lgkmcnt(0)" ::: "memory");  // same-wave RAW on LDS
    const int rb = (lo * 128 + hi * 16) ^ ((lo & 7) << 4);
    const bf16x8 pa0 = *reinterpret_cast<const bf16x8*>(plw + rb);
    const bf16x8 pa1 = *reinterpret_cast<const bf16x8*>(plw + (rb ^ 64));

    // ---- PV: o[nd] += P[16q x 64k] @ V[64k x 16d] ----
    const short* vbase = vT + ((long)(b * 1024 + h * 64)) * 1024 + kb * 64;
    __builtin_amdgcn_s_setprio(1);
    #pragma unroll
    for (int nd = 0; nd < 4; ++nd) {
      bf16x8 v0 = *reinterpret_cast<const bf16x8*>(vbase + (long)(nd * 16 + lo) * 1024 + hi * 8);
      bf16x8 v1 = *reinterpret_cast<const bf16x8*>(vbase + (long)(nd * 16 + lo) * 1024 + 32 + hi * 8);
      o[nd] = mfma16x16x32(pa0, v0, o[nd]);
      o[nd] = mfma16x16x32(pa1, v1, o[nd]);
    }
    __builtin_amdgcn_s_setprio(0);
  }

  #pragma unroll
  for (int r = 0; r < 4; ++r) {
    const float invl = 1.0f / l_r[r];
    float* drow = dst + (long)(b * 512 + q0 + 4 * hi + r) * 1024 + h * 64;
    #pragma unroll
    for (int nd = 0; nd < 4; ++nd) drow[nd * 16 + lo] = o[nd][r] * invl;
  }
}

// ---------------- host ----------------
extern "C" void kernel_launch(void* const* d_in, const int* in_sizes, int n_in,
                              void* d_out, int out_size, void* d_ws, size_t ws_size,
                              hipStream_t stream) {
  const int*   ids  = (const int*)d_in[0];
  const float* enc  = (const float*)d_in[1];
  const float* mask = (const float*)d_in[2];
  const float* emb  = (const float*)d_in[3];
  const float* ln_g = (const float*)d_in[4];
  const float* ln_b = (const float*)d_in[5];
  const float* wq   = (const float*)d_in[6];
  const float* bq   = (const float*)d_in[7];
  const float* wk   = (const float*)d_in[8];
  const float* bk   = (const float*)d_in[9];
  const float* wv   = (const float*)d_in[10];
  const float* bv   = (const float*)d_in[11];
  float* out = (float*)d_out;

  char* ws = (char*)d_ws;
  short* encB  = (short*)ws; ws += (long)8192 * 1024 * 2;
  short* wqT   = (short*)ws; ws += (long)4 * 1024 * 1024 * 2;
  short* wkvT  = (short*)ws; ws += (long)4 * 2048 * 1024 * 2;
  float* xbuf  = (float*)ws; ws += (long)4096 * 1024 * 4;
  short* hbuf  = (short*)ws; ws += (long)4096 * 1024 * 2;
  short* qbuf  = (short*)ws; ws += (long)4096 * 1024 * 2;
  short* kbuf4 = (short*)ws; ws += (long)4 * 8192 * 1024 * 2;  // [layer][tok][1024]
  short* vT4   = (short*)ws; ws += (long)4 * 8192 * 1024 * 2;  // [layer][b][d][tok]

  conv_bf16_kernel<<<8192, 256, 0, stream>>>(enc, encB);
  transpose_w_kernel<<<dim3(32, 32, 12), dim3(32, 8), 0, stream>>>(wq, wk, wv, wqT, wkvT);
  gather_kernel<<<4096, 256, 0, stream>>>(ids, emb, xbuf);

  // All 4 layers' K/V projections in one dispatch (x-independent).
  gemm_kernel<1><<<dim3(64, 64), 256, 0, stream>>>(
      encB, wkvT, bk, bv, kbuf4, vT4);

  for (int i = 0; i < 4; ++i) {
    ln_kernel<<<4096, 256, 0, stream>>>(xbuf, ln_g + i * 1024, ln_b + i * 1024, hbuf);
    gemm_kernel<0><<<dim3(32, 8), 256, 0, stream>>>(
        hbuf, wqT + (long)i * 1024 * 1024, bq + i * 1024, nullptr, qbuf, nullptr);
    float* dst = (i == 3) ? out : xbuf;
    attn_kernel<<<dim3(128, 8), 256, 0, stream>>>(
        qbuf, kbuf4 + (long)i * 8388608, vT4 + (long)i * 8388608, mask, dst);
  }
}